// Round 7
// baseline (346.331 us; speedup 1.0000x reference)
//
#include <hip/hip_runtime.h>
#include <hip/hip_bf16.h>

typedef unsigned short u16;
typedef short bf16x8 __attribute__((ext_vector_type(8)));
typedef float f32x4 __attribute__((ext_vector_type(4)));
typedef float f32x2 __attribute__((ext_vector_type(2)));

__device__ __forceinline__ u16 f2b(float f) {
    unsigned x = __float_as_uint(f);
    return (u16)((x + 0x7fffu + ((x >> 16) & 1u)) >> 16);
}

// pack two f32 to bf16x2 by truncation: one v_perm_b32
__device__ __forceinline__ int pkbf(float lo, float hi) {
    return __builtin_amdgcn_perm(__float_as_uint(hi), __float_as_uint(lo), 0x07060302);
}

// packed dual-f32 FMA: acc = f * ex + acc (VOP3P)
__device__ __forceinline__ void pkfma(f32x2& acc, f32x2 f, f32x2 ex) {
    asm("v_pk_fma_f32 %0, %1, %2, %0" : "+v"(acc) : "v"(f), "v"(ex));
}

__global__ void cast_wt_kernel(const float* __restrict__ W, u16* __restrict__ Wt) {
    int idx = blockIdx.x * blockDim.x + threadIdx.x;  // 512*512
    int n = idx >> 9, k = idx & 511;
    Wt[idx] = f2b(W[k * 512 + n]);
}

// ---------------- GEMM fused: f32 A staging + h8 (fp8, HEAD-MAJOR) + attention logits ----------
// grid (4 heads fastest, 2*Mpad/128 row tiles). A read straight from x/wtx (f32),
// truncated to bf16 at LDS->reg. h8 layout [head][R2][128]; asrc/adst layout [head][R2].
__global__ __launch_bounds__(256, 2) void gemm_fused2(
    const float* __restrict__ xA, const float* __restrict__ xW, const u16* __restrict__ Bt,
    unsigned char* __restrict__ h8, const float* __restrict__ att_src,
    const float* __restrict__ att_dst, float* __restrict__ asrc, float* __restrict__ adst,
    int N, int Mpad) {
    __shared__ float lA[128 * 32];
    __shared__ u16 lB[128 * 32];
    __shared__ float sred[2][128][2];
    const int tid = threadIdx.x;
    const int w = tid >> 6, l = tid & 63;
    const int row0 = blockIdx.y * 128;
    const int head = blockIdx.x;
    const int col0 = head * 128;
    const int wr = w >> 1, wc = w & 1;
    const int mlane = l & 15, quad = l >> 4;
    const int R2v = 2 * Mpad;

    const float* src = (row0 >= Mpad) ? xW : xA;
    const int rbase = row0 - (row0 >= Mpad ? Mpad : 0);
    // A staging: lane covers row (g*32 + w*8 + l/8), floats (l&7)*4
    const int arow = (w << 3) + (l >> 3);
    const int acol = (l & 7) << 2;
    // B staging: as before (bf16)
    const int srow = (w << 4) + (l >> 2);
    const int scol = (l & 3) << 3;

    f32x4 acc[4][4];
#pragma unroll
    for (int i = 0; i < 4; i++)
#pragma unroll
        for (int j = 0; j < 4; j++) acc[i][j] = f32x4{0.f, 0.f, 0.f, 0.f};

    for (int k0 = 0; k0 < 512; k0 += 32) {
#pragma unroll
        for (int g = 0; g < 4; ++g) {
            int lrow = rbase + g * 32 + arow;
            lrow = min(lrow, N - 1);  // pad rows: clamp (results are don't-care)
            const float* ga = src + (size_t)lrow * 512 + k0 + acol;
            float* la = lA + (g * 32 + (w << 3)) * 32;  // wave-uniform base
            __builtin_amdgcn_global_load_lds((const __attribute__((address_space(1))) void*)ga,
                                             (__attribute__((address_space(3))) void*)la, 16, 0, 0);
        }
#pragma unroll
        for (int s = 0; s < 2; ++s) {
            const u16* gb = Bt + (size_t)(col0 + s * 64 + srow) * 512 + (k0 + scol);
            u16* lb = lB + s * 2048 + w * 512;
            __builtin_amdgcn_global_load_lds((const __attribute__((address_space(1))) void*)gb,
                                             (__attribute__((address_space(3))) void*)lb, 16, 0, 0);
        }
        __syncthreads();
        bf16x8 af[4], bfr[4];
#pragma unroll
        for (int i = 0; i < 4; i++) {
            const float* ap = &lA[(wr * 64 + i * 16 + mlane) * 32 + quad * 8];
            float4 f0 = *(const float4*)ap;
            float4 f1 = *(const float4*)(ap + 4);
            int* ai = (int*)&af[i];
            ai[0] = pkbf(f0.x, f0.y);
            ai[1] = pkbf(f0.z, f0.w);
            ai[2] = pkbf(f1.x, f1.y);
            ai[3] = pkbf(f1.z, f1.w);
            bfr[i] = *(const bf16x8*)&lB[(wc * 64 + i * 16 + mlane) * 32 + quad * 8];
        }
#pragma unroll
        for (int i = 0; i < 4; i++)
#pragma unroll
            for (int j = 0; j < 4; j++)
                acc[i][j] = __builtin_amdgcn_mfma_f32_16x16x32_bf16(af[i], bfr[j], acc[i][j], 0, 0, 0);
        __syncthreads();
    }

    float as_j[4], ad_j[4];
#pragma unroll
    for (int j = 0; j < 4; j++) {
        as_j[j] = att_src[col0 + wc * 64 + j * 16 + mlane];
        ad_j[j] = att_dst[col0 + wc * 64 + j * 16 + mlane];
    }
#pragma unroll
    for (int i = 0; i < 4; i++) {
#pragma unroll
        for (int r = 0; r < 4; r++) {
            float vs = 0.f, vd = 0.f;
#pragma unroll
            for (int j = 0; j < 4; j++) {
                float hv = acc[i][j][r];
                vs += hv * as_j[j];
                vd += hv * ad_j[j];
            }
#pragma unroll
            for (int o = 8; o >= 1; o >>= 1) {
                vs += __shfl_xor(vs, o);
                vd += __shfl_xor(vd, o);
            }
            if (mlane == 0) {
                int lrow = wr * 64 + i * 16 + quad * 4 + r;
                sred[0][lrow][wc] = vs;
                sred[1][lrow][wc] = vd;
            }
        }
    }
#pragma unroll
    for (int i = 0; i < 4; i++)
#pragma unroll
        for (int j = 0; j < 4; j++)
#pragma unroll
            for (int r = 0; r < 4; r++) {
                int rg = row0 + wr * 64 + i * 16 + quad * 4 + r;
                int cc = wc * 64 + j * 16 + mlane;  // within-head channel [0,128)
                float v = acc[i][j][r];
                unsigned pk = __builtin_amdgcn_cvt_pk_fp8_f32(v, v, 0, false);
                h8[(((size_t)(head * R2v + rg)) << 7) + cc] = (unsigned char)(pk & 0xff);
            }
    __syncthreads();
    {
        int row = tid & 127, which = tid >> 7;
        int rg = row0 + row;  // hrow
        float v = sred[which][row][0] + sred[which][row][1];
        (which ? adst : asrc)[head * R2v + rg] = v;
    }
}

// ---------------- CSR over hrow space [0, 2*Mpad) ----------------
__global__ void csr_count(const int* __restrict__ adj, const int* __restrict__ wadj,
                          int E, int Mpad, int* __restrict__ deg) {
    int i = blockIdx.x * blockDim.x + threadIdx.x;
    if (i < 2 * E) {
        int d = (i < E) ? adj[E + i] : (wadj[E + (i - E)] + Mpad);
        atomicAdd(&deg[d], 1);
    }
}

// scanA over n=2*Mpad rows; +1 self-loop for valid (non-pad) rows
__global__ __launch_bounds__(256) void scanA(const int* __restrict__ deg, int* __restrict__ off,
                                             int* __restrict__ bsum, int n, int N, int Mpad) {
    __shared__ int wsum[4];
    int tid = threadIdx.x, lane = tid & 63, wid = tid >> 6;
    int i = blockIdx.x * 256 + tid;
    int valid = (i < N) || (i >= Mpad && i < Mpad + N);
    int d = (i < n) ? deg[i] + (valid ? 1 : 0) : 0;
    int x = d;
#pragma unroll
    for (int o = 1; o < 64; o <<= 1) {
        int y = __shfl_up(x, (unsigned)o, 64);
        if (lane >= o) x += y;
    }
    if (lane == 63) wsum[wid] = x;
    __syncthreads();
    int woff = 0;
    for (int j = 0; j < wid; ++j) woff += wsum[j];
    if (i < n) off[i] = woff + x - d;
    if (tid == 255) bsum[blockIdx.x] = woff + x;
}

__global__ __launch_bounds__(256) void scanB(const int* __restrict__ bsum, int* __restrict__ bbase,
                                             int nb, int* __restrict__ off, int n) {
    __shared__ int wsum[4];
    int tid = threadIdx.x, lane = tid & 63, wid = tid >> 6;
    int d = (tid < nb) ? bsum[tid] : 0;
    int x = d;
#pragma unroll
    for (int o = 1; o < 64; o <<= 1) {
        int y = __shfl_up(x, (unsigned)o, 64);
        if (lane >= o) x += y;
    }
    if (lane == 63) wsum[wid] = x;
    __syncthreads();
    int woff = 0;
    for (int j = 0; j < wid; ++j) woff += wsum[j];
    int excl = woff + x - d;
    if (tid < nb) bbase[tid] = excl;
    if (tid == nb - 1) off[n] = excl + d;
}

__global__ void scanC(int* __restrict__ off, const int* __restrict__ bbase,
                      int* __restrict__ cursor, int* __restrict__ csrc, int n, int N, int Mpad) {
    int i = blockIdx.x * blockDim.x + threadIdx.x;
    if (i < n) {
        int o = off[i] + bbase[i >> 8];
        off[i] = o;
        int valid = (i < N) || (i >= Mpad && i < Mpad + N);
        if (valid) csrc[o] = i;  // self loop (hrow)
        cursor[i] = o + valid;
    }
}

__global__ void csr_scatter(const int* __restrict__ adj, const int* __restrict__ wadj,
                            int E, int Mpad, int* __restrict__ cursor, int* __restrict__ csrc) {
    int i = blockIdx.x * blockDim.x + threadIdx.x;
    if (i < 2 * E) {
        int s, d;
        if (i < E) {
            s = adj[i];
            d = adj[E + i];
        } else {
            s = wadj[i - E] + Mpad;
            d = wadj[E + (i - E)] + Mpad;
        }
        int p = atomicAdd(&cursor[d], 1);
        csrc[p] = s;
    }
}

// ---------------- fused softmax + gather v12: leader-lane loads + unroll2 + oversubscribe ----
// Same (head,graph)-per-XCD split and 3-deep pipeline as v11, but:
//  - csrc/ash loaded only by lane (l&7)==0 of each 8-lane edge-group (8 TA addrs, not 64),
//    broadcast via __shfl (ds_bpermute).
//  - #pragma unroll 2 removes pipeline-rotation movs.
//  - 4096 blocks (2x oversubscription) to backfill draining CUs in the tail.
__global__ __launch_bounds__(256, 4) void gat_aggregate12(
    const unsigned char* __restrict__ h8, const float* __restrict__ asrc,
    const float* __restrict__ adst, const int* __restrict__ off, const int* __restrict__ csrc,
    const float* __restrict__ bias, float* __restrict__ partAB, int Mpad) {
    const int R2 = 2 * Mpad;
    __shared__ float spool[128];  // this block's (head, graph) 128 channels
    int tid = threadIdx.x;
    if (tid < 128) spool[tid] = 0.f;
    __syncthreads();
    const int wv = tid >> 6, l = tid & 63;
    const int gi = (l >> 3) & 3;   // edge slot within half (0..3)
    const int hi = l >> 5;         // which dst of the pair (0/1)
    const int chb = (l & 7) << 4;  // channel byte offset within 128 (16 B per lane)
    const bool lead = (l & 7) == 0;
    const int lsrc = l & 56;       // leader lane of my 8-lane group
    const int head = (blockIdx.x & 7) >> 1;
    const int gc = blockIdx.x & 1;  // graph 0=A, 1=B
    const unsigned char* h8h = h8 + (((size_t)head * R2) << 7);
    const float* ash = asrc + (size_t)head * R2;
    const float* adh = adst + (size_t)head * R2;
    float bb[16];
#pragma unroll
    for (int k = 0; k < 16; ++k) bb[k] = bias[head * 128 + chb + k];
    float pool[16];
#pragma unroll
    for (int k = 0; k < 16; ++k) pool[k] = 0.f;

    const int hb = gc * Mpad;
    const int half = Mpad >> 1;  // Mpad even; N even -> pairs never split valid/pad
    // dense wave index within this (head,graph) class: 512 blocks x 4 waves = [0,2048)
    int widx = ((blockIdx.x >> 3) << 2) + wv;

    for (int p = widx; p < half; p += 2048) {
        int d0 = (p << 1) + hb;
        int q0 = off[d0], q1 = off[d0 + 1], q2 = off[d0 + 2];
        int n0 = q1 - q0, n1 = q2 - q1;
        int nmax = max(n0, n1);
        if (nmax == 0) continue;  // pad pair
        int nm = hi ? n1 : n0;
        int qm = hi ? q1 : q0;
        float ad = adh[d0 + hi];
        f32x2 acc2[8];
#pragma unroll
        for (int j = 0; j < 8; ++j) acc2[j] = f32x2{0.f, 0.f};
        float dsum = 0.f;

        // prologue (leader lanes own csrc/ash; every lane gathers its own h8 16B)
        int E2L = 0, E3L = 0;
        float A0L = 0.f, A1L = 0.f;
        int4 H0, H1;
        {
            int Ea = 0, Eb = 0;
            if (lead) {
                Ea = csrc[qm + ((gi < nm) ? gi : 0)];
                Eb = csrc[qm + ((4 + gi < nm) ? 4 + gi : 0)];
                E2L = csrc[qm + ((8 + gi < nm) ? 8 + gi : 0)];
                E3L = csrc[qm + ((12 + gi < nm) ? 12 + gi : 0)];
                A0L = ash[Ea];
                A1L = ash[Eb];
            }
            int E0 = __shfl(Ea, lsrc);
            int E1 = __shfl(Eb, lsrc);
            H0 = *(const int4*)(h8h + (((size_t)E0) << 7) + chb);
            H1 = *(const int4*)(h8h + (((size_t)E1) << 7) + chb);
        }

#pragma unroll 2
        for (int base = 0; base < nmax; base += 4) {
            // leader: csrc for iter k+4, ash for iter k+2 (leader already holds E2L)
            int E4L = 0;
            float A2L = 0.f;
            if (lead) {
                int i4 = base + 16 + gi;
                E4L = csrc[qm + ((i4 < nm) ? i4 : 0)];
                A2L = ash[E2L];
            }
            // broadcast E for iter k+2, gather h8 (per-lane 16B)
            int E2 = __shfl(E2L, lsrc);
            int4 H2 = *(const int4*)(h8h + (((size_t)E2) << 7) + chb);
            // broadcast ash for iter k, compute
            float A0 = __shfl(A0L, lsrc);
            float e = A0 + ad;
            float em = fmaxf(e, 0.2f * e);
            float ex = __expf(em);
            ex = ((base + gi) < nm) ? ex : 0.f;
            dsum += ex;
            f32x2 exv = {ex, ex};
            f32x2 f;
            f = __builtin_amdgcn_cvt_pk_f32_fp8(H0.x, false); pkfma(acc2[0], f, exv);
            f = __builtin_amdgcn_cvt_pk_f32_fp8(H0.x, true);  pkfma(acc2[1], f, exv);
            f = __builtin_amdgcn_cvt_pk_f32_fp8(H0.y, false); pkfma(acc2[2], f, exv);
            f = __builtin_amdgcn_cvt_pk_f32_fp8(H0.y, true);  pkfma(acc2[3], f, exv);
            f = __builtin_amdgcn_cvt_pk_f32_fp8(H0.z, false); pkfma(acc2[4], f, exv);
            f = __builtin_amdgcn_cvt_pk_f32_fp8(H0.z, true);  pkfma(acc2[5], f, exv);
            f = __builtin_amdgcn_cvt_pk_f32_fp8(H0.w, false); pkfma(acc2[6], f, exv);
            f = __builtin_amdgcn_cvt_pk_f32_fp8(H0.w, true);  pkfma(acc2[7], f, exv);
            // rotate pipeline (renamed away by unroll 2)
            A0L = A1L; A1L = A2L;
            E2L = E3L; E3L = E4L;
            H0 = H1; H1 = H2;
        }
        // reduce across the 4 edge-slot groups (xor 8,16 stay within each 32-lane half)
        dsum += __shfl_xor(dsum, 8);
        dsum += __shfl_xor(dsum, 16);
#pragma unroll
        for (int j = 0; j < 8; ++j) {
            acc2[j].x += __shfl_xor(acc2[j].x, 8);
            acc2[j].y += __shfl_xor(acc2[j].y, 8);
            acc2[j].x += __shfl_xor(acc2[j].x, 16);
            acc2[j].y += __shfl_xor(acc2[j].y, 16);
        }
        if (nm > 0) {
            float inv = 1.f / (dsum + 1e-16f);
#pragma unroll
            for (int j = 0; j < 8; ++j) {
                float o0 = acc2[j].x * inv + bb[2 * j];
                float o1 = acc2[j].y * inv + bb[2 * j + 1];
                pool[2 * j] += fmaxf(o0, 0.01f * o0);
                pool[2 * j + 1] += fmaxf(o1, 0.01f * o1);
            }
        }
    }
    // pools replicated across the 4 slot groups of each half -> group 0 of each half commits
    if ((l & 31) < 8) {
#pragma unroll
        for (int k = 0; k < 16; ++k) atomicAdd(&spool[chb + k], pool[k]);
    }
    __syncthreads();
    if (tid < 128) {
        int slot = (blockIdx.x >> 3) & 63;
        float* dp = partAB + (gc ? 64 * 512 : 0) + (slot << 9) + head * 128 + tid;
        atomicAdd(dp, spool[tid]);
    }
}

// ---------------- fused mean-pool reduce + fc + concat ----------------
__global__ __launch_bounds__(256) void fc_final2(
    const float* __restrict__ partAB, const float* __restrict__ w, const float* __restrict__ b,
    float* __restrict__ out, float invN) {
    __shared__ float gA[512], gB[512];
    __shared__ float rA[256], rB[256];
    int t = threadIdx.x;
    for (int i = t; i < 512; i += 256) {
        float sA = 0.f, sB = 0.f;
        for (int r = 0; r < 64; ++r) {
            sA += partAB[r * 512 + i];
            sB += partAB[64 * 512 + r * 512 + i];
        }
        gA[i] = sA * invN;
        gB[i] = sB * invN;
    }
    __syncthreads();
    int jj = t & 31, ks = t >> 5;
    int j = blockIdx.x * 32 + jj;
    float sA = 0.f, sB = 0.f;
    for (int k = ks * 64; k < ks * 64 + 64; ++k) {
        float wv = w[k * 512 + j];
        sA += gA[k] * wv;
        sB += gB[k] * wv;
    }
    rA[t] = sA;
    rB[t] = sB;
    __syncthreads();
    if (ks == 0) {
#pragma unroll
        for (int s2 = 1; s2 < 8; ++s2) {
            sA += rA[jj + 32 * s2];
            sB += rB[jj + 32 * s2];
        }
        sA += b[j];
        sB += b[j];
        sA = sA >= 0.f ? sA : 0.01f * sA;
        sB = sB >= 0.f ? sB : 0.01f * sB;
        out[j] = sA;
        out[512 + j] = sB;
        out[1024 + j] = sA - sB;
    }
}

// ---------------- launch ----------------
extern "C" void kernel_launch(void* const* d_in, const int* in_sizes, int n_in,
                              void* d_out, int out_size, void* d_ws, size_t ws_size,
                              hipStream_t stream) {
    const float* x = (const float*)d_in[0];
    const int* adj = (const int*)d_in[1];
    const float* wtx = (const float*)d_in[2];
    const int* wadj = (const int*)d_in[3];
    const float* W = (const float*)d_in[4];
    const float* att_s = (const float*)d_in[5];
    const float* att_d = (const float*)d_in[6];
    const float* bias = (const float*)d_in[7];
    const float* fc1w = (const float*)d_in[8];
    const float* fc1b = (const float*)d_in[9];
    float* out = (float*)d_out;

    const int N = in_sizes[0] / 512;  // 20000
    const int E = in_sizes[1] / 2;    // 320000
    const int Mpad = ((N + 127) / 128) * 128;
    const int R2 = 2 * Mpad;          // hrow space
    const int nb = (R2 + 255) / 256;  // 157

    char* p = (char*)d_ws;
    auto alloc = [&](size_t bytes) -> char* {
        char* r = p;
        p += (bytes + 255) & ~(size_t)255;
        return r;
    };
    unsigned char* h8 = (unsigned char*)alloc((size_t)R2 * 512);
    u16* Wt = (u16*)alloc(512 * 512 * 2);
    float* asrc = (float*)alloc((size_t)R2 * 4 * 4);
    float* adst = (float*)alloc((size_t)R2 * 4 * 4);
    int* deg = (int*)alloc((size_t)R2 * 4);
    int* off = (int*)alloc((size_t)(R2 + 1) * 4);
    int* cursor = (int*)alloc((size_t)R2 * 4);
    int* bsum = (int*)alloc(256 * 4);
    int* bbase = (int*)alloc(256 * 4);
    int* csrc = (int*)alloc((size_t)2 * (E + N) * 4);
    float* partAB = (float*)alloc((size_t)2 * 64 * 512 * 4);

    hipMemsetAsync(partAB, 0, (size_t)2 * 64 * 512 * 4, stream);
    hipMemsetAsync(deg, 0, (size_t)R2 * 4, stream);
    cast_wt_kernel<<<(512 * 512) / 256, 256, 0, stream>>>(W, Wt);

    // CSR build (independent of GEMM)
    csr_count<<<(2 * E + 255) / 256, 256, 0, stream>>>(adj, wadj, E, Mpad, deg);
    scanA<<<nb, 256, 0, stream>>>(deg, off, bsum, R2, N, Mpad);
    scanB<<<1, 256, 0, stream>>>(bsum, bbase, nb, off, R2);
    scanC<<<nb, 256, 0, stream>>>(off, bbase, cursor, csrc, R2, N, Mpad);
    csr_scatter<<<(2 * E + 255) / 256, 256, 0, stream>>>(adj, wadj, E, Mpad, cursor, csrc);

    // fused GEMM from f32 inputs (head fastest -> A-stripe reuse)
    dim3 gg(4, R2 / 128, 1);
    gemm_fused2<<<gg, 256, 0, stream>>>(x, wtx, Wt, h8, att_s, att_d, asrc, adst, N, Mpad);

    gat_aggregate12<<<4096, 256, 0, stream>>>(h8, asrc, adst, off, csrc, bias, partAB, Mpad);

    fc_final2<<<16, 256, 0, stream>>>(partAB, fc1w, fc1b, out, 1.0f / (float)N);
}

// Round 8
// 342.269 us; speedup vs baseline: 1.0119x; 1.0119x over previous
//
#include <hip/hip_runtime.h>
#include <hip/hip_bf16.h>

typedef unsigned short u16;
typedef short bf16x8 __attribute__((ext_vector_type(8)));
typedef float f32x4 __attribute__((ext_vector_type(4)));
typedef float f32x2 __attribute__((ext_vector_type(2)));

__device__ __forceinline__ u16 f2b(float f) {
    unsigned x = __float_as_uint(f);
    return (u16)((x + 0x7fffu + ((x >> 16) & 1u)) >> 16);
}

// pack two f32 to bf16x2 by truncation: one v_perm_b32
__device__ __forceinline__ int pkbf(float lo, float hi) {
    return __builtin_amdgcn_perm(__float_as_uint(hi), __float_as_uint(lo), 0x07060302);
}

// packed dual-f32 FMA: acc = f * ex + acc (VOP3P)
__device__ __forceinline__ void pkfma(f32x2& acc, f32x2 f, f32x2 ex) {
    asm("v_pk_fma_f32 %0, %1, %2, %0" : "+v"(acc) : "v"(f), "v"(ex));
}

__global__ void cast_wt_kernel(const float* __restrict__ W, u16* __restrict__ Wt) {
    int idx = blockIdx.x * blockDim.x + threadIdx.x;  // 512*512
    int n = idx >> 9, k = idx & 511;
    Wt[idx] = f2b(W[k * 512 + n]);
}

// ---------------- GEMM fused v3: one block = 64 rows x ALL 512 cols, wave = head ----------
// A panel staged ONCE per row-tile (was 4x, once per head-block): 329 MB -> 82 MB A traffic.
// Per k-step each wave runs 32 MFMA on 4 shared A-frags (2x better MFMA:VALU than 128x128).
// Wave w == head w owns cols [128w,128w+128): asrc/adst written directly (no LDS round-trip).
// h8 layout [head][R2][128]; asrc/adst layout [head][R2].
__global__ __launch_bounds__(256, 2) void gemm_fused3(
    const float* __restrict__ xA, const float* __restrict__ xW, const u16* __restrict__ Bt,
    unsigned char* __restrict__ h8, const float* __restrict__ att_src,
    const float* __restrict__ att_dst, float* __restrict__ asrc, float* __restrict__ adst,
    int N, int Mpad) {
    __shared__ float lA[64 * 32];   // 8 KB
    __shared__ u16 lB[512 * 32];    // 32 KB
    const int tid = threadIdx.x;
    const int w = tid >> 6, l = tid & 63;   // wave w = head w
    const int row0 = blockIdx.x * 64;
    const int head = w;
    const int mlane = l & 15, quad = l >> 4;
    const int R2v = 2 * Mpad;

    const float* src = (row0 >= Mpad) ? xW : xA;
    const int rbase = row0 - (row0 >= Mpad ? Mpad : 0);
    // A staging: wave w covers rows [16w,16w+16): inst g in {0,1}, lane covers
    // row 16w+8g+(l>>3), f32 col (l&7)*4
    const int arow = (l >> 3);
    const int acol = (l & 7) << 2;
    // B staging: wave w covers Bt rows [128w,128w+128): inst s in 0..7, lane covers
    // row 128w+16s+(l>>2), bf16 col (l&3)*8
    const int brow = (l >> 2);
    const int bcol = (l & 3) << 3;

    f32x4 acc[4][8];
#pragma unroll
    for (int i = 0; i < 4; i++)
#pragma unroll
        for (int j = 0; j < 8; j++) acc[i][j] = f32x4{0.f, 0.f, 0.f, 0.f};

    for (int k0 = 0; k0 < 512; k0 += 32) {
#pragma unroll
        for (int g = 0; g < 2; ++g) {
            int lrow = rbase + (w << 4) + (g << 3) + arow;
            lrow = min(lrow, N - 1);  // pad rows: clamp (results are don't-care)
            const float* ga = src + (size_t)lrow * 512 + k0 + acol;
            float* la = lA + (((w << 4) + (g << 3)) << 5);  // wave-uniform base
            __builtin_amdgcn_global_load_lds((const __attribute__((address_space(1))) void*)ga,
                                             (__attribute__((address_space(3))) void*)la, 16, 0, 0);
        }
#pragma unroll
        for (int s = 0; s < 8; ++s) {
            const u16* gb = Bt + (size_t)((w << 7) + (s << 4) + brow) * 512 + (k0 + bcol);
            u16* lb = lB + (((w << 7) + (s << 4)) << 5);  // wave-uniform base
            __builtin_amdgcn_global_load_lds((const __attribute__((address_space(1))) void*)gb,
                                             (__attribute__((address_space(3))) void*)lb, 16, 0, 0);
        }
        __syncthreads();
        bf16x8 af[4], bfr[8];
#pragma unroll
        for (int i = 0; i < 4; i++) {
            const float* ap = &lA[(i * 16 + mlane) * 32 + quad * 8];
            float4 f0 = *(const float4*)ap;
            float4 f1 = *(const float4*)(ap + 4);
            int* ai = (int*)&af[i];
            ai[0] = pkbf(f0.x, f0.y);
            ai[1] = pkbf(f0.z, f0.w);
            ai[2] = pkbf(f1.x, f1.y);
            ai[3] = pkbf(f1.z, f1.w);
        }
#pragma unroll
        for (int j = 0; j < 8; j++)
            bfr[j] = *(const bf16x8*)&lB[((w << 7) + j * 16 + mlane) * 32 + quad * 8];
#pragma unroll
        for (int i = 0; i < 4; i++)
#pragma unroll
            for (int j = 0; j < 8; j++)
                acc[i][j] = __builtin_amdgcn_mfma_f32_16x16x32_bf16(af[i], bfr[j], acc[i][j], 0, 0, 0);
        __syncthreads();
    }

    float as_j[8], ad_j[8];
#pragma unroll
    for (int j = 0; j < 8; j++) {
        as_j[j] = att_src[(head << 7) + j * 16 + mlane];
        ad_j[j] = att_dst[(head << 7) + j * 16 + mlane];
    }
#pragma unroll
    for (int i = 0; i < 4; i++) {
#pragma unroll
        for (int r = 0; r < 4; r++) {
            float vs = 0.f, vd = 0.f;
#pragma unroll
            for (int j = 0; j < 8; j++) {
                float hv = acc[i][j][r];
                vs += hv * as_j[j];
                vd += hv * ad_j[j];
            }
#pragma unroll
            for (int o = 8; o >= 1; o >>= 1) {
                vs += __shfl_xor(vs, o);
                vd += __shfl_xor(vd, o);
            }
            if (mlane == 0) {
                int rg = row0 + i * 16 + quad * 4 + r;
                asrc[head * R2v + rg] = vs;
                adst[head * R2v + rg] = vd;
            }
        }
    }
#pragma unroll
    for (int i = 0; i < 4; i++)
#pragma unroll
        for (int j = 0; j < 8; j++)
#pragma unroll
            for (int r = 0; r < 4; r++) {
                int rg = row0 + i * 16 + quad * 4 + r;
                int cc = j * 16 + mlane;  // within-head channel [0,128)
                float v = acc[i][j][r];
                unsigned pk = __builtin_amdgcn_cvt_pk_fp8_f32(v, v, 0, false);
                h8[(((size_t)(head * R2v + rg)) << 7) + cc] = (unsigned char)(pk & 0xff);
            }
}

// ---------------- CSR over hrow space [0, 2*Mpad) ----------------
__global__ void csr_count(const int* __restrict__ adj, const int* __restrict__ wadj,
                          int E, int Mpad, int* __restrict__ deg) {
    int i = blockIdx.x * blockDim.x + threadIdx.x;
    if (i < 2 * E) {
        int d = (i < E) ? adj[E + i] : (wadj[E + (i - E)] + Mpad);
        atomicAdd(&deg[d], 1);
    }
}

// scanA over n=2*Mpad rows; +1 self-loop for valid (non-pad) rows
__global__ __launch_bounds__(256) void scanA(const int* __restrict__ deg, int* __restrict__ off,
                                             int* __restrict__ bsum, int n, int N, int Mpad) {
    __shared__ int wsum[4];
    int tid = threadIdx.x, lane = tid & 63, wid = tid >> 6;
    int i = blockIdx.x * 256 + tid;
    int valid = (i < N) || (i >= Mpad && i < Mpad + N);
    int d = (i < n) ? deg[i] + (valid ? 1 : 0) : 0;
    int x = d;
#pragma unroll
    for (int o = 1; o < 64; o <<= 1) {
        int y = __shfl_up(x, (unsigned)o, 64);
        if (lane >= o) x += y;
    }
    if (lane == 63) wsum[wid] = x;
    __syncthreads();
    int woff = 0;
    for (int j = 0; j < wid; ++j) woff += wsum[j];
    if (i < n) off[i] = woff + x - d;
    if (tid == 255) bsum[blockIdx.x] = woff + x;
}

__global__ __launch_bounds__(256) void scanB(const int* __restrict__ bsum, int* __restrict__ bbase,
                                             int nb, int* __restrict__ off, int n) {
    __shared__ int wsum[4];
    int tid = threadIdx.x, lane = tid & 63, wid = tid >> 6;
    int d = (tid < nb) ? bsum[tid] : 0;
    int x = d;
#pragma unroll
    for (int o = 1; o < 64; o <<= 1) {
        int y = __shfl_up(x, (unsigned)o, 64);
        if (lane >= o) x += y;
    }
    if (lane == 63) wsum[wid] = x;
    __syncthreads();
    int woff = 0;
    for (int j = 0; j < wid; ++j) woff += wsum[j];
    int excl = woff + x - d;
    if (tid < nb) bbase[tid] = excl;
    if (tid == nb - 1) off[n] = excl + d;
}

__global__ void scanC(int* __restrict__ off, const int* __restrict__ bbase,
                      int* __restrict__ cursor, int* __restrict__ csrc, int n, int N, int Mpad) {
    int i = blockIdx.x * blockDim.x + threadIdx.x;
    if (i < n) {
        int o = off[i] + bbase[i >> 8];
        off[i] = o;
        int valid = (i < N) || (i >= Mpad && i < Mpad + N);
        if (valid) csrc[o] = i;  // self loop (hrow)
        cursor[i] = o + valid;
    }
}

__global__ void csr_scatter(const int* __restrict__ adj, const int* __restrict__ wadj,
                            int E, int Mpad, int* __restrict__ cursor, int* __restrict__ csrc) {
    int i = blockIdx.x * blockDim.x + threadIdx.x;
    if (i < 2 * E) {
        int s, d;
        if (i < E) {
            s = adj[i];
            d = adj[E + i];
        } else {
            s = wadj[i - E] + Mpad;
            d = wadj[E + (i - E)] + Mpad;
        }
        int p = atomicAdd(&cursor[d], 1);
        csrc[p] = s;
    }
}

// ---------------- fused softmax + gather v11: (head,graph)-per-XCD, 3-deep pipeline ----------
// (reverted to r6 best: 86.5 us. v12's shfl-broadcast variant regressed — ds_bpermute + lgkmcnt
// costs more than redundant same-address lane loads, which the TA broadcasts for free.)
__global__ __launch_bounds__(256, 4) void gat_aggregate11(
    const unsigned char* __restrict__ h8, const float* __restrict__ asrc,
    const float* __restrict__ adst, const int* __restrict__ off, const int* __restrict__ csrc,
    const float* __restrict__ bias, float* __restrict__ partAB, int Mpad) {
    const int R2 = 2 * Mpad;
    __shared__ float spool[128];  // this block's (head, graph) 128 channels
    int tid = threadIdx.x;
    if (tid < 128) spool[tid] = 0.f;
    __syncthreads();
    const int wv = tid >> 6, l = tid & 63;
    const int gi = (l >> 3) & 3;  // edge slot within half (0..3)
    const int hi = l >> 5;        // which dst of the pair (0/1)
    const int chb = (l & 7) << 4; // channel byte offset within 128 (16 B per lane)
    const int head = (blockIdx.x & 7) >> 1;
    const int gc = blockIdx.x & 1;  // graph 0=A, 1=B
    const unsigned char* h8h = h8 + (((size_t)head * R2) << 7);
    const float* ash = asrc + (size_t)head * R2;
    const float* adh = adst + (size_t)head * R2;
    float bb[16];
#pragma unroll
    for (int k = 0; k < 16; ++k) bb[k] = bias[head * 128 + chb + k];
    float pool[16];
#pragma unroll
    for (int k = 0; k < 16; ++k) pool[k] = 0.f;

    const int hb = gc * Mpad;
    const int half = Mpad >> 1;  // Mpad even; N even -> pairs never split valid/pad
    // dense wave index within this (head,graph) class: 256 blocks x 4 waves = [0,1024)
    int widx = ((blockIdx.x >> 3) << 2) + wv;

    for (int p = widx; p < half; p += 1024) {
        int d0 = (p << 1) + hb;
        int q0 = off[d0], q1 = off[d0 + 1], q2 = off[d0 + 2];
        int n0 = q1 - q0, n1 = q2 - q1;
        int nmax = max(n0, n1);
        if (nmax == 0) continue;  // pad pair
        int nm = hi ? n1 : n0;
        int qm = hi ? q1 : q0;
        float ad = adh[d0 + hi];
        f32x2 acc2[8];
#pragma unroll
        for (int j = 0; j < 8; ++j) acc2[j] = f32x2{0.f, 0.f};
        float dsum = 0.f;

        // prologue: csrc for k=0..3, gathers for k=0,1  (clamped indices are always valid:
        // nm>=1 for any processed pair, so qm+0 is in-segment)
        int i0 = gi, i1 = 4 + gi, i2 = 8 + gi, i3 = 12 + gi;
        int E0 = csrc[qm + ((i0 < nm) ? i0 : 0)];
        int E1 = csrc[qm + ((i1 < nm) ? i1 : 0)];
        int E2 = csrc[qm + ((i2 < nm) ? i2 : 0)];
        int E3 = csrc[qm + ((i3 < nm) ? i3 : 0)];
        float A0 = ash[E0];
        int4 H0 = *(const int4*)(h8h + (((size_t)E0) << 7) + chb);
        float A1 = ash[E1];
        int4 H1 = *(const int4*)(h8h + (((size_t)E1) << 7) + chb);

        for (int base = 0; base < nmax; base += 4) {
            // issue csrc for iter k+4
            int i4 = base + 16 + gi;
            int E4 = csrc[qm + ((i4 < nm) ? i4 : 0)];
            // issue gathers for iter k+2 (E2 was loaded 2 iterations ago)
            float A2 = ash[E2];
            int4 H2 = *(const int4*)(h8h + (((size_t)E2) << 7) + chb);
            // compute iter k (A0/H0 issued 2 iterations ago)
            float e = A0 + ad;
            float em = fmaxf(e, 0.2f * e);
            float ex = __expf(em);
            ex = ((base + gi) < nm) ? ex : 0.f;
            dsum += ex;
            f32x2 exv = {ex, ex};
            f32x2 f;
            f = __builtin_amdgcn_cvt_pk_f32_fp8(H0.x, false); pkfma(acc2[0], f, exv);
            f = __builtin_amdgcn_cvt_pk_f32_fp8(H0.x, true);  pkfma(acc2[1], f, exv);
            f = __builtin_amdgcn_cvt_pk_f32_fp8(H0.y, false); pkfma(acc2[2], f, exv);
            f = __builtin_amdgcn_cvt_pk_f32_fp8(H0.y, true);  pkfma(acc2[3], f, exv);
            f = __builtin_amdgcn_cvt_pk_f32_fp8(H0.z, false); pkfma(acc2[4], f, exv);
            f = __builtin_amdgcn_cvt_pk_f32_fp8(H0.z, true);  pkfma(acc2[5], f, exv);
            f = __builtin_amdgcn_cvt_pk_f32_fp8(H0.w, false); pkfma(acc2[6], f, exv);
            f = __builtin_amdgcn_cvt_pk_f32_fp8(H0.w, true);  pkfma(acc2[7], f, exv);
            // rotate pipeline
            A0 = A1; H0 = H1;
            A1 = A2; H1 = H2;
            E2 = E3; E3 = E4;
        }
        // reduce across the 4 edge-slot groups (xor 8,16 stay within each 32-lane half)
        dsum += __shfl_xor(dsum, 8);
        dsum += __shfl_xor(dsum, 16);
#pragma unroll
        for (int j = 0; j < 8; ++j) {
            acc2[j].x += __shfl_xor(acc2[j].x, 8);
            acc2[j].y += __shfl_xor(acc2[j].y, 8);
            acc2[j].x += __shfl_xor(acc2[j].x, 16);
            acc2[j].y += __shfl_xor(acc2[j].y, 16);
        }
        if (nm > 0) {
            float inv = 1.f / (dsum + 1e-16f);
#pragma unroll
            for (int j = 0; j < 8; ++j) {
                float o0 = acc2[j].x * inv + bb[2 * j];
                float o1 = acc2[j].y * inv + bb[2 * j + 1];
                pool[2 * j] += fmaxf(o0, 0.01f * o0);
                pool[2 * j + 1] += fmaxf(o1, 0.01f * o1);
            }
        }
    }
    // pools replicated across the 4 slot groups of each half -> group 0 of each half commits
    if ((l & 31) < 8) {
#pragma unroll
        for (int k = 0; k < 16; ++k) atomicAdd(&spool[chb + k], pool[k]);
    }
    __syncthreads();
    if (tid < 128) {
        int slot = (blockIdx.x >> 3) & 63;
        float* dp = partAB + (gc ? 64 * 512 : 0) + (slot << 9) + head * 128 + tid;
        atomicAdd(dp, spool[tid]);
    }
}

// ---------------- fused mean-pool reduce + fc + concat ----------------
__global__ __launch_bounds__(256) void fc_final2(
    const float* __restrict__ partAB, const float* __restrict__ w, const float* __restrict__ b,
    float* __restrict__ out, float invN) {
    __shared__ float gA[512], gB[512];
    __shared__ float rA[256], rB[256];
    int t = threadIdx.x;
    for (int i = t; i < 512; i += 256) {
        float sA = 0.f, sB = 0.f;
        for (int r = 0; r < 64; ++r) {
            sA += partAB[r * 512 + i];
            sB += partAB[64 * 512 + r * 512 + i];
        }
        gA[i] = sA * invN;
        gB[i] = sB * invN;
    }
    __syncthreads();
    int jj = t & 31, ks = t >> 5;
    int j = blockIdx.x * 32 + jj;
    float sA = 0.f, sB = 0.f;
    for (int k = ks * 64; k < ks * 64 + 64; ++k) {
        float wv = w[k * 512 + j];
        sA += gA[k] * wv;
        sB += gB[k] * wv;
    }
    rA[t] = sA;
    rB[t] = sB;
    __syncthreads();
    if (ks == 0) {
#pragma unroll
        for (int s2 = 1; s2 < 8; ++s2) {
            sA += rA[jj + 32 * s2];
            sB += rB[jj + 32 * s2];
        }
        sA += b[j];
        sB += b[j];
        sA = sA >= 0.f ? sA : 0.01f * sA;
        sB = sB >= 0.f ? sB : 0.01f * sB;
        out[j] = sA;
        out[512 + j] = sB;
        out[1024 + j] = sA - sB;
    }
}

// ---------------- launch ----------------
extern "C" void kernel_launch(void* const* d_in, const int* in_sizes, int n_in,
                              void* d_out, int out_size, void* d_ws, size_t ws_size,
                              hipStream_t stream) {
    const float* x = (const float*)d_in[0];
    const int* adj = (const int*)d_in[1];
    const float* wtx = (const float*)d_in[2];
    const int* wadj = (const int*)d_in[3];
    const float* W = (const float*)d_in[4];
    const float* att_s = (const float*)d_in[5];
    const float* att_d = (const float*)d_in[6];
    const float* bias = (const float*)d_in[7];
    const float* fc1w = (const float*)d_in[8];
    const float* fc1b = (const float*)d_in[9];
    float* out = (float*)d_out;

    const int N = in_sizes[0] / 512;  // 20000
    const int E = in_sizes[1] / 2;    // 320000
    const int Mpad = ((N + 127) / 128) * 128;
    const int R2 = 2 * Mpad;          // hrow space
    const int nb = (R2 + 255) / 256;  // 157

    char* p = (char*)d_ws;
    auto alloc = [&](size_t bytes) -> char* {
        char* r = p;
        p += (bytes + 255) & ~(size_t)255;
        return r;
    };
    unsigned char* h8 = (unsigned char*)alloc((size_t)R2 * 512);
    u16* Wt = (u16*)alloc(512 * 512 * 2);
    float* asrc = (float*)alloc((size_t)R2 * 4 * 4);
    float* adst = (float*)alloc((size_t)R2 * 4 * 4);
    int* deg = (int*)alloc((size_t)R2 * 4);
    int* off = (int*)alloc((size_t)(R2 + 1) * 4);
    int* cursor = (int*)alloc((size_t)R2 * 4);
    int* bsum = (int*)alloc(256 * 4);
    int* bbase = (int*)alloc(256 * 4);
    int* csrc = (int*)alloc((size_t)2 * (E + N) * 4);
    float* partAB = (float*)alloc((size_t)2 * 64 * 512 * 4);

    hipMemsetAsync(partAB, 0, (size_t)2 * 64 * 512 * 4, stream);
    hipMemsetAsync(deg, 0, (size_t)R2 * 4, stream);
    cast_wt_kernel<<<(512 * 512) / 256, 256, 0, stream>>>(W, Wt);

    // CSR build (independent of GEMM)
    csr_count<<<(2 * E + 255) / 256, 256, 0, stream>>>(adj, wadj, E, Mpad, deg);
    scanA<<<nb, 256, 0, stream>>>(deg, off, bsum, R2, N, Mpad);
    scanB<<<1, 256, 0, stream>>>(bsum, bbase, nb, off, R2);
    scanC<<<nb, 256, 0, stream>>>(off, bbase, cursor, csrc, R2, N, Mpad);
    csr_scatter<<<(2 * E + 255) / 256, 256, 0, stream>>>(adj, wadj, E, Mpad, cursor, csrc);

    // fused GEMM: one block per 64-row tile, all heads (A staged once)
    gemm_fused3<<<R2 / 64, 256, 0, stream>>>(x, wtx, Wt, h8, att_s, att_d, asrc, adst, N, Mpad);

    gat_aggregate11<<<2048, 256, 0, stream>>>(h8, asrc, adst, off, csrc, bias, partAB, Mpad);

    fc_final2<<<16, 256, 0, stream>>>(partAB, fc1w, fc1b, out, 1.0f / (float)N);
}

// Round 9
// 332.309 us; speedup vs baseline: 1.0422x; 1.0300x over previous
//
#include <hip/hip_runtime.h>
#include <hip/hip_bf16.h>

typedef unsigned short u16;
typedef short bf16x8 __attribute__((ext_vector_type(8)));
typedef float f32x4 __attribute__((ext_vector_type(4)));
typedef float f32x2 __attribute__((ext_vector_type(2)));

__device__ __forceinline__ u16 f2b(float f) {
    unsigned x = __float_as_uint(f);
    return (u16)((x + 0x7fffu + ((x >> 16) & 1u)) >> 16);
}

// pack two f32 to bf16x2 by truncation: one v_perm_b32
__device__ __forceinline__ int pkbf(float lo, float hi) {
    return __builtin_amdgcn_perm(__float_as_uint(hi), __float_as_uint(lo), 0x07060302);
}

// packed dual-f32 FMA: acc = f * ex + acc (VOP3P)
__device__ __forceinline__ void pkfma(f32x2& acc, f32x2 f, f32x2 ex) {
    asm("v_pk_fma_f32 %0, %1, %2, %0" : "+v"(acc) : "v"(f), "v"(ex));
}

// ---------------- W^T cast: 64x64 LDS tile transpose, coalesced both sides ----------------
__global__ __launch_bounds__(256) void cast_wt_kernel(const float* __restrict__ W,
                                                      u16* __restrict__ Wt) {
    __shared__ u16 tile[64][65];
    int tx = threadIdx.x & 63, ty = threadIdx.x >> 6;  // 64 x 4
    int bx = blockIdx.x & 7, by = blockIdx.x >> 3;
    // read W rows [by*64..), cols [bx*64..): tx fast over cols -> coalesced
#pragma unroll
    for (int r = 0; r < 16; ++r) {
        int row = ty + (r << 2);
        tile[tx][row] = f2b(W[(by * 64 + row) * 512 + bx * 64 + tx]);
    }
    __syncthreads();
    // write Wt[n][k] = W[k][n]: n = bx*64+row, k = by*64+tx; tx fast -> coalesced
#pragma unroll
    for (int r = 0; r < 16; ++r) {
        int row = ty + (r << 2);
        Wt[(bx * 64 + row) * 512 + by * 64 + tx] = tile[row][tx];
    }
}

// ---------------- GEMM fused v3: one block = 64 rows x ALL 512 cols, wave = head ----------
// h8 layout [head][R2][128]; asrc/adst layout [head][R2].
__global__ __launch_bounds__(256, 2) void gemm_fused3(
    const float* __restrict__ xA, const float* __restrict__ xW, const u16* __restrict__ Bt,
    unsigned char* __restrict__ h8, const float* __restrict__ att_src,
    const float* __restrict__ att_dst, float* __restrict__ asrc, float* __restrict__ adst,
    int N, int Mpad) {
    __shared__ float lA[64 * 32];   // 8 KB
    __shared__ u16 lB[512 * 32];    // 32 KB
    const int tid = threadIdx.x;
    const int w = tid >> 6, l = tid & 63;   // wave w = head w
    const int row0 = blockIdx.x * 64;
    const int head = w;
    const int mlane = l & 15, quad = l >> 4;
    const int R2v = 2 * Mpad;

    const float* src = (row0 >= Mpad) ? xW : xA;
    const int rbase = row0 - (row0 >= Mpad ? Mpad : 0);
    const int arow = (l >> 3);
    const int acol = (l & 7) << 2;
    const int brow = (l >> 2);
    const int bcol = (l & 3) << 3;

    f32x4 acc[4][8];
#pragma unroll
    for (int i = 0; i < 4; i++)
#pragma unroll
        for (int j = 0; j < 8; j++) acc[i][j] = f32x4{0.f, 0.f, 0.f, 0.f};

    for (int k0 = 0; k0 < 512; k0 += 32) {
#pragma unroll
        for (int g = 0; g < 2; ++g) {
            int lrow = rbase + (w << 4) + (g << 3) + arow;
            lrow = min(lrow, N - 1);  // pad rows: clamp (results are don't-care)
            const float* ga = src + (size_t)lrow * 512 + k0 + acol;
            float* la = lA + (((w << 4) + (g << 3)) << 5);  // wave-uniform base
            __builtin_amdgcn_global_load_lds((const __attribute__((address_space(1))) void*)ga,
                                             (__attribute__((address_space(3))) void*)la, 16, 0, 0);
        }
#pragma unroll
        for (int s = 0; s < 8; ++s) {
            const u16* gb = Bt + (size_t)((w << 7) + (s << 4) + brow) * 512 + (k0 + bcol);
            u16* lb = lB + (((w << 7) + (s << 4)) << 5);  // wave-uniform base
            __builtin_amdgcn_global_load_lds((const __attribute__((address_space(1))) void*)gb,
                                             (__attribute__((address_space(3))) void*)lb, 16, 0, 0);
        }
        __syncthreads();
        bf16x8 af[4], bfr[8];
#pragma unroll
        for (int i = 0; i < 4; i++) {
            const float* ap = &lA[(i * 16 + mlane) * 32 + quad * 8];
            float4 f0 = *(const float4*)ap;
            float4 f1 = *(const float4*)(ap + 4);
            int* ai = (int*)&af[i];
            ai[0] = pkbf(f0.x, f0.y);
            ai[1] = pkbf(f0.z, f0.w);
            ai[2] = pkbf(f1.x, f1.y);
            ai[3] = pkbf(f1.z, f1.w);
        }
#pragma unroll
        for (int j = 0; j < 8; j++)
            bfr[j] = *(const bf16x8*)&lB[((w << 7) + j * 16 + mlane) * 32 + quad * 8];
#pragma unroll
        for (int i = 0; i < 4; i++)
#pragma unroll
            for (int j = 0; j < 8; j++)
                acc[i][j] = __builtin_amdgcn_mfma_f32_16x16x32_bf16(af[i], bfr[j], acc[i][j], 0, 0, 0);
        __syncthreads();
    }

    float as_j[8], ad_j[8];
#pragma unroll
    for (int j = 0; j < 8; j++) {
        as_j[j] = att_src[(head << 7) + j * 16 + mlane];
        ad_j[j] = att_dst[(head << 7) + j * 16 + mlane];
    }
#pragma unroll
    for (int i = 0; i < 4; i++) {
#pragma unroll
        for (int r = 0; r < 4; r++) {
            float vs = 0.f, vd = 0.f;
#pragma unroll
            for (int j = 0; j < 8; j++) {
                float hv = acc[i][j][r];
                vs += hv * as_j[j];
                vd += hv * ad_j[j];
            }
#pragma unroll
            for (int o = 8; o >= 1; o >>= 1) {
                vs += __shfl_xor(vs, o);
                vd += __shfl_xor(vd, o);
            }
            if (mlane == 0) {
                int rg = row0 + i * 16 + quad * 4 + r;
                asrc[head * R2v + rg] = vs;
                adst[head * R2v + rg] = vd;
            }
        }
    }
#pragma unroll
    for (int i = 0; i < 4; i++)
#pragma unroll
        for (int j = 0; j < 8; j++)
#pragma unroll
            for (int r = 0; r < 4; r++) {
                int rg = row0 + i * 16 + quad * 4 + r;
                int cc = j * 16 + mlane;  // within-head channel [0,128)
                float v = acc[i][j][r];
                unsigned pk = __builtin_amdgcn_cvt_pk_fp8_f32(v, v, 0, false);
                h8[(((size_t)(head * R2v + rg)) << 7) + cc] = (unsigned char)(pk & 0xff);
            }
}

// ---------------- CSR over hrow space [0, 2*Mpad) ----------------
__global__ void csr_count(const int* __restrict__ adj, const int* __restrict__ wadj,
                          int E, int Mpad, int* __restrict__ deg) {
    int i = blockIdx.x * blockDim.x + threadIdx.x;
    if (i < 2 * E) {
        int d = (i < E) ? adj[E + i] : (wadj[E + (i - E)] + Mpad);
        atomicAdd(&deg[d], 1);
    }
}

// scanA over n=2*Mpad rows; +1 self-loop for valid (non-pad) rows
__global__ __launch_bounds__(256) void scanA(const int* __restrict__ deg, int* __restrict__ off,
                                             int* __restrict__ bsum, int n, int N, int Mpad) {
    __shared__ int wsum[4];
    int tid = threadIdx.x, lane = tid & 63, wid = tid >> 6;
    int i = blockIdx.x * 256 + tid;
    int valid = (i < N) || (i >= Mpad && i < Mpad + N);
    int d = (i < n) ? deg[i] + (valid ? 1 : 0) : 0;
    int x = d;
#pragma unroll
    for (int o = 1; o < 64; o <<= 1) {
        int y = __shfl_up(x, (unsigned)o, 64);
        if (lane >= o) x += y;
    }
    if (lane == 63) wsum[wid] = x;
    __syncthreads();
    int woff = 0;
    for (int j = 0; j < wid; ++j) woff += wsum[j];
    if (i < n) off[i] = woff + x - d;
    if (tid == 255) bsum[blockIdx.x] = woff + x;
}

__global__ __launch_bounds__(256) void scanB(const int* __restrict__ bsum, int* __restrict__ bbase,
                                             int nb, int* __restrict__ off, int n) {
    __shared__ int wsum[4];
    int tid = threadIdx.x, lane = tid & 63, wid = tid >> 6;
    int d = (tid < nb) ? bsum[tid] : 0;
    int x = d;
#pragma unroll
    for (int o = 1; o < 64; o <<= 1) {
        int y = __shfl_up(x, (unsigned)o, 64);
        if (lane >= o) x += y;
    }
    if (lane == 63) wsum[wid] = x;
    __syncthreads();
    int woff = 0;
    for (int j = 0; j < wid; ++j) woff += wsum[j];
    int excl = woff + x - d;
    if (tid < nb) bbase[tid] = excl;
    if (tid == nb - 1) off[n] = excl + d;
}

__global__ void scanC(int* __restrict__ off, const int* __restrict__ bbase,
                      int* __restrict__ cursor, int* __restrict__ csrc, int n, int N, int Mpad) {
    int i = blockIdx.x * blockDim.x + threadIdx.x;
    if (i < n) {
        int o = off[i] + bbase[i >> 8];
        off[i] = o;
        int valid = (i < N) || (i >= Mpad && i < Mpad + N);
        if (valid) csrc[o] = i;  // self loop (hrow)
        cursor[i] = o + valid;
    }
}

__global__ void csr_scatter(const int* __restrict__ adj, const int* __restrict__ wadj,
                            int E, int Mpad, int* __restrict__ cursor, int* __restrict__ csrc) {
    int i = blockIdx.x * blockDim.x + threadIdx.x;
    if (i < 2 * E) {
        int s, d;
        if (i < E) {
            s = adj[i];
            d = adj[E + i];
        } else {
            s = wadj[i - E] + Mpad;
            d = wadj[E + (i - E)] + Mpad;
        }
        int p = atomicAdd(&cursor[d], 1);
        csrc[p] = s;
    }
}

// ---------------- fused softmax + gather v13: v11 + 6 blocks/CU single round + unroll2 ------
// (head,graph)-per-XCD split and 3-deep pipeline as v11. Grid 1536 = 256 CU x 6 co-resident
// blocks (one round, no inter-round drain); unroll 2 renames away pipeline-rotation movs.
__global__ __launch_bounds__(256, 6) void gat_aggregate13(
    const unsigned char* __restrict__ h8, const float* __restrict__ asrc,
    const float* __restrict__ adst, const int* __restrict__ off, const int* __restrict__ csrc,
    const float* __restrict__ bias, float* __restrict__ partAB, int Mpad) {
    const int R2 = 2 * Mpad;
    __shared__ float spool[128];  // this block's (head, graph) 128 channels
    int tid = threadIdx.x;
    if (tid < 128) spool[tid] = 0.f;
    __syncthreads();
    const int wv = tid >> 6, l = tid & 63;
    const int gi = (l >> 3) & 3;  // edge slot within half (0..3)
    const int hi = l >> 5;        // which dst of the pair (0/1)
    const int chb = (l & 7) << 4; // channel byte offset within 128 (16 B per lane)
    const int head = (blockIdx.x & 7) >> 1;
    const int gc = blockIdx.x & 1;  // graph 0=A, 1=B
    const unsigned char* h8h = h8 + (((size_t)head * R2) << 7);
    const float* ash = asrc + (size_t)head * R2;
    const float* adh = adst + (size_t)head * R2;
    float bb[16];
#pragma unroll
    for (int k = 0; k < 16; ++k) bb[k] = bias[head * 128 + chb + k];
    float pool[16];
#pragma unroll
    for (int k = 0; k < 16; ++k) pool[k] = 0.f;

    const int hb = gc * Mpad;
    const int half = Mpad >> 1;  // Mpad even; N even -> pairs never split valid/pad
    // dense wave index within this (head,graph) class; class size = gridDim/8 blocks * 4 waves
    int widx = ((blockIdx.x >> 3) << 2) + wv;
    const int cstride = gridDim.x >> 1;  // (gridDim/8)*4

    for (int p = widx; p < half; p += cstride) {
        int d0 = (p << 1) + hb;
        int q0 = off[d0], q1 = off[d0 + 1], q2 = off[d0 + 2];
        int n0 = q1 - q0, n1 = q2 - q1;
        int nmax = max(n0, n1);
        if (nmax == 0) continue;  // pad pair
        int nm = hi ? n1 : n0;
        int qm = hi ? q1 : q0;
        float ad = adh[d0 + hi];
        f32x2 acc2[8];
#pragma unroll
        for (int j = 0; j < 8; ++j) acc2[j] = f32x2{0.f, 0.f};
        float dsum = 0.f;

        // prologue: csrc for k=0..3, gathers for k=0,1 (clamped idx always in-segment: nm>=1)
        int i0 = gi, i1 = 4 + gi, i2 = 8 + gi, i3 = 12 + gi;
        int E0 = csrc[qm + ((i0 < nm) ? i0 : 0)];
        int E1 = csrc[qm + ((i1 < nm) ? i1 : 0)];
        int E2 = csrc[qm + ((i2 < nm) ? i2 : 0)];
        int E3 = csrc[qm + ((i3 < nm) ? i3 : 0)];
        float A0 = ash[E0];
        int4 H0 = *(const int4*)(h8h + (((size_t)E0) << 7) + chb);
        float A1 = ash[E1];
        int4 H1 = *(const int4*)(h8h + (((size_t)E1) << 7) + chb);

#pragma unroll 2
        for (int base = 0; base < nmax; base += 4) {
            // issue csrc for iter k+4
            int i4 = base + 16 + gi;
            int E4 = csrc[qm + ((i4 < nm) ? i4 : 0)];
            // issue gathers for iter k+2 (E2 was loaded 2 iterations ago)
            float A2 = ash[E2];
            int4 H2 = *(const int4*)(h8h + (((size_t)E2) << 7) + chb);
            // compute iter k (A0/H0 issued 2 iterations ago)
            float e = A0 + ad;
            float em = fmaxf(e, 0.2f * e);
            float ex = __expf(em);
            ex = ((base + gi) < nm) ? ex : 0.f;
            dsum += ex;
            f32x2 exv = {ex, ex};
            f32x2 f;
            f = __builtin_amdgcn_cvt_pk_f32_fp8(H0.x, false); pkfma(acc2[0], f, exv);
            f = __builtin_amdgcn_cvt_pk_f32_fp8(H0.x, true);  pkfma(acc2[1], f, exv);
            f = __builtin_amdgcn_cvt_pk_f32_fp8(H0.y, false); pkfma(acc2[2], f, exv);
            f = __builtin_amdgcn_cvt_pk_f32_fp8(H0.y, true);  pkfma(acc2[3], f, exv);
            f = __builtin_amdgcn_cvt_pk_f32_fp8(H0.z, false); pkfma(acc2[4], f, exv);
            f = __builtin_amdgcn_cvt_pk_f32_fp8(H0.z, true);  pkfma(acc2[5], f, exv);
            f = __builtin_amdgcn_cvt_pk_f32_fp8(H0.w, false); pkfma(acc2[6], f, exv);
            f = __builtin_amdgcn_cvt_pk_f32_fp8(H0.w, true);  pkfma(acc2[7], f, exv);
            // rotate pipeline (renamed away by unroll 2)
            A0 = A1; H0 = H1;
            A1 = A2; H1 = H2;
            E2 = E3; E3 = E4;
        }
        // reduce across the 4 edge-slot groups (xor 8,16 stay within each 32-lane half)
        dsum += __shfl_xor(dsum, 8);
        dsum += __shfl_xor(dsum, 16);
#pragma unroll
        for (int j = 0; j < 8; ++j) {
            acc2[j].x += __shfl_xor(acc2[j].x, 8);
            acc2[j].y += __shfl_xor(acc2[j].y, 8);
            acc2[j].x += __shfl_xor(acc2[j].x, 16);
            acc2[j].y += __shfl_xor(acc2[j].y, 16);
        }
        if (nm > 0) {
            float inv = 1.f / (dsum + 1e-16f);
#pragma unroll
            for (int j = 0; j < 8; ++j) {
                float o0 = acc2[j].x * inv + bb[2 * j];
                float o1 = acc2[j].y * inv + bb[2 * j + 1];
                pool[2 * j] += fmaxf(o0, 0.01f * o0);
                pool[2 * j + 1] += fmaxf(o1, 0.01f * o1);
            }
        }
    }
    // pools replicated across the 4 slot groups of each half -> group 0 of each half commits
    if ((l & 31) < 8) {
#pragma unroll
        for (int k = 0; k < 16; ++k) atomicAdd(&spool[chb + k], pool[k]);
    }
    __syncthreads();
    if (tid < 128) {
        int slot = (blockIdx.x >> 3) & 63;
        float* dp = partAB + (gc ? 64 * 512 : 0) + (slot << 9) + head * 128 + tid;
        atomicAdd(dp, spool[tid]);
    }
}

// ---------------- fused mean-pool reduce + fc + concat ----------------
__global__ __launch_bounds__(256) void fc_final2(
    const float* __restrict__ partAB, const float* __restrict__ w, const float* __restrict__ b,
    float* __restrict__ out, float invN) {
    __shared__ float gA[512], gB[512];
    __shared__ float rA[256], rB[256];
    int t = threadIdx.x;
    for (int i = t; i < 512; i += 256) {
        float sA = 0.f, sB = 0.f;
        for (int r = 0; r < 64; ++r) {
            sA += partAB[r * 512 + i];
            sB += partAB[64 * 512 + r * 512 + i];
        }
        gA[i] = sA * invN;
        gB[i] = sB * invN;
    }
    __syncthreads();
    int jj = t & 31, ks = t >> 5;
    int j = blockIdx.x * 32 + jj;
    float sA = 0.f, sB = 0.f;
    for (int k = ks * 64; k < ks * 64 + 64; ++k) {
        float wv = w[k * 512 + j];
        sA += gA[k] * wv;
        sB += gB[k] * wv;
    }
    rA[t] = sA;
    rB[t] = sB;
    __syncthreads();
    if (ks == 0) {
#pragma unroll
        for (int s2 = 1; s2 < 8; ++s2) {
            sA += rA[jj + 32 * s2];
            sB += rB[jj + 32 * s2];
        }
        sA += b[j];
        sB += b[j];
        sA = sA >= 0.f ? sA : 0.01f * sA;
        sB = sB >= 0.f ? sB : 0.01f * sB;
        out[j] = sA;
        out[512 + j] = sB;
        out[1024 + j] = sA - sB;
    }
}

// ---------------- launch ----------------
extern "C" void kernel_launch(void* const* d_in, const int* in_sizes, int n_in,
                              void* d_out, int out_size, void* d_ws, size_t ws_size,
                              hipStream_t stream) {
    const float* x = (const float*)d_in[0];
    const int* adj = (const int*)d_in[1];
    const float* wtx = (const float*)d_in[2];
    const int* wadj = (const int*)d_in[3];
    const float* W = (const float*)d_in[4];
    const float* att_s = (const float*)d_in[5];
    const float* att_d = (const float*)d_in[6];
    const float* bias = (const float*)d_in[7];
    const float* fc1w = (const float*)d_in[8];
    const float* fc1b = (const float*)d_in[9];
    float* out = (float*)d_out;

    const int N = in_sizes[0] / 512;  // 20000
    const int E = in_sizes[1] / 2;    // 320000
    const int Mpad = ((N + 127) / 128) * 128;
    const int R2 = 2 * Mpad;          // hrow space
    const int nb = (R2 + 255) / 256;  // 157

    char* p = (char*)d_ws;
    auto alloc = [&](size_t bytes) -> char* {
        char* r = p;
        p += (bytes + 255) & ~(size_t)255;
        return r;
    };
    unsigned char* h8 = (unsigned char*)alloc((size_t)R2 * 512);
    u16* Wt = (u16*)alloc(512 * 512 * 2);
    float* asrc = (float*)alloc((size_t)R2 * 4 * 4);
    float* adst = (float*)alloc((size_t)R2 * 4 * 4);
    int* deg = (int*)alloc((size_t)R2 * 4);
    int* off = (int*)alloc((size_t)(R2 + 1) * 4);
    int* cursor = (int*)alloc((size_t)R2 * 4);
    int* bsum = (int*)alloc(256 * 4);
    int* bbase = (int*)alloc(256 * 4);
    int* csrc = (int*)alloc((size_t)2 * (E + N) * 4);
    float* partAB = (float*)alloc((size_t)2 * 64 * 512 * 4);

    hipMemsetAsync(partAB, 0, (size_t)2 * 64 * 512 * 4, stream);
    hipMemsetAsync(deg, 0, (size_t)R2 * 4, stream);
    cast_wt_kernel<<<64, 256, 0, stream>>>(W, Wt);

    // CSR build (independent of GEMM)
    csr_count<<<(2 * E + 255) / 256, 256, 0, stream>>>(adj, wadj, E, Mpad, deg);
    scanA<<<nb, 256, 0, stream>>>(deg, off, bsum, R2, N, Mpad);
    scanB<<<1, 256, 0, stream>>>(bsum, bbase, nb, off, R2);
    scanC<<<nb, 256, 0, stream>>>(off, bbase, cursor, csrc, R2, N, Mpad);
    csr_scatter<<<(2 * E + 255) / 256, 256, 0, stream>>>(adj, wadj, E, Mpad, cursor, csrc);

    // fused GEMM: one block per 64-row tile, all heads (A staged once)
    gemm_fused3<<<R2 / 64, 256, 0, stream>>>(x, wtx, Wt, h8, att_s, att_d, asrc, adst, N, Mpad);

    gat_aggregate13<<<1536, 256, 0, stream>>>(h8, asrc, adst, off, csrc, bias, partAB, Mpad);

    fc_final2<<<16, 256, 0, stream>>>(partAB, fc1w, fc1b, out, 1.0f / (float)N);
}